// Round 7
// baseline (265.235 us; speedup 1.0000x reference)
//
#include <hip/hip_runtime.h>
#include <math.h>

// B=4, L=1024, D=512, H=8, d=64
#define L_ 1024
#define D_ 512

typedef _Float16 half8 __attribute__((ext_vector_type(8)));
typedef _Float16 half4v __attribute__((ext_vector_type(4)));
typedef _Float16 half2v __attribute__((ext_vector_type(2)));
typedef float floatx4 __attribute__((ext_vector_type(4)));

#define LDS_PITCH 264   // halves per staged row (16B-aligned, proven conflict-free)

// ---------- prep: K,Q -> fp16 straight; V -> fp16 transposed Vt[b][h][d][m]
__global__ __launch_bounds__(256) void prep(
    const float* __restrict__ K, const float* __restrict__ Q,
    const float* __restrict__ V,
    _Float16* __restrict__ K16, _Float16* __restrict__ Q16,
    _Float16* __restrict__ Vt)
{
    __shared__ _Float16 tile[64][72];
    const int t = threadIdx.x;
    const int bi = blockIdx.x;
    if (bi < 2048) {
        #pragma unroll
        for (int it = 0; it < 2; ++it) {
            size_t f = (size_t)bi * 512 + it * 256 + t;
            const float4* src; _Float16* dst;
            if (f < 524288) { src = (const float4*)K; dst = K16; }
            else            { src = (const float4*)Q; dst = Q16; f -= 524288; }
            float4 v = src[f];
            half4v h = { (_Float16)v.x, (_Float16)v.y, (_Float16)v.z, (_Float16)v.w };
            *(half4v*)&dst[f * 4] = h;
        }
    } else {
        const int id = bi - 2048;           // 512 blocks: 4b x 8h x 16 mtiles
        const int mt = id & 15, h = (id >> 4) & 7, b = id >> 7;
        const float4* Vf4 = (const float4*)V;
        for (int it = 0; it < 4; ++it) {
            const int ml = (t >> 4) + 16 * it;
            const int c4 = t & 15;
            float4 v = Vf4[(size_t)(b * 1024 + mt * 64 + ml) * 128 + h * 16 + c4];
            tile[c4 * 4 + 0][ml] = (_Float16)v.x;
            tile[c4 * 4 + 1][ml] = (_Float16)v.y;
            tile[c4 * 4 + 2][ml] = (_Float16)v.z;
            tile[c4 * 4 + 3][ml] = (_Float16)v.w;
        }
        __syncthreads();
        const int d = t >> 2, seg = t & 3;
        half8 o0 = *(half8*)&tile[d][seg * 16];
        half8 o1 = *(half8*)&tile[d][seg * 16 + 8];
        size_t obase = ((size_t)(b * 8 + h) * 64 + d) * 1024 + mt * 64 + seg * 16;
        *(half8*)&Vt[obase] = o0;
        *(half8*)&Vt[obase + 8] = o1;
    }
}

// ---------- qk_ln: e = exp(LN(K.Q^T) - M) via fp16 MFMA, masked, stored
// coalesced to S[b][h][l][m] via LDS. TWO h-PASSES: pass p recomputes the
// (cheap, 3%-utilized) MFMAs + LN stats and stages/stores only heads
// 4p..4p+3 (64 rows) -> LDS halves to 33.8 KB -> 4 blocks/CU (2x waves).
// Store pattern, segment sizes, and summation order are bit-identical to
// the proven 54-us configuration.
// M = max_h(2.8285*|gamma_h|+|beta_h|) is a data-independent LN output bound,
// so no per-row max pass is needed (exp never overflows).
__global__ __launch_bounds__(256) void qk_ln(
    const _Float16* __restrict__ K16, const _Float16* __restrict__ Q16,
    const float* __restrict__ gamma, const float* __restrict__ beta,
    const float* __restrict__ doc,
    _Float16* __restrict__ S, float* __restrict__ spart)
{
    __shared__ _Float16 se[64 * LDS_PITCH];   // 33792 B -> 4 blocks/CU

    const int t  = threadIdx.x;
    const int bi = blockIdx.x;              // 1024 = 4b x 64 lt x 4 q
    const int b  = bi & 3;
    const int lt = (bi >> 2) & 63;
    const int q  = bi >> 8;
    const int wv = t >> 6, lane = t & 63;
    const int col = lane & 15, quad = lane >> 4;
    const int len = (int)doc[b];
    const int lbase = lt * 16;

    float g[8], be[8], M = 0.f;
    #pragma unroll
    for (int h = 0; h < 8; ++h) {
        g[h] = gamma[h]; be[h] = beta[h];
        M = fmaxf(M, 2.8285f * fabsf(g[h]) + fabsf(be[h]));
    }

    const _Float16* Kb = K16 + (size_t)b * 524288;
    const _Float16* Qb = Q16 + (size_t)b * 524288;
    const size_t krow = (size_t)(lbase + col) * 512;

    half8 a0[8], a1[8];
    #pragma unroll
    for (int h = 0; h < 8; ++h) {
        a0[h] = *(const half8*)&Kb[krow + h * 64 + quad * 8];
        a1[h] = *(const half8*)&Kb[krow + h * 64 + 32 + quad * 8];
    }

    float sum[8][4];
    #pragma unroll
    for (int h = 0; h < 8; ++h)
        #pragma unroll
        for (int r = 0; r < 4; ++r) sum[h][r] = 0.f;

    #pragma unroll
    for (int pass = 0; pass < 2; ++pass) {
        const int h0 = pass * 4;
        for (int mt = 0; mt < 4; ++mt) {
            const int m0 = q * 256 + wv * 64 + mt * 16;
            const size_t qrow = (size_t)(m0 + col) * 512;
            floatx4 c[8];
            #pragma unroll
            for (int h = 0; h < 8; ++h) {
                half8 b0 = *(const half8*)&Qb[qrow + h * 64 + quad * 8];
                half8 b1 = *(const half8*)&Qb[qrow + h * 64 + 32 + quad * 8];
                floatx4 z = {0.f, 0.f, 0.f, 0.f};
                z    = __builtin_amdgcn_mfma_f32_16x16x32_f16(a0[h], b0, z, 0, 0, 0);
                c[h] = __builtin_amdgcn_mfma_f32_16x16x32_f16(a1[h], b1, z, 0, 0, 0);
            }
            const bool mok = (m0 + col) < len;
            #pragma unroll
            for (int r = 0; r < 4; ++r) {
                const int l = lbase + quad * 4 + r;
                float mu = 0.f;
                #pragma unroll
                for (int h = 0; h < 8; ++h) mu += c[h][r];
                mu *= 0.125f;
                float var = 0.f;
                #pragma unroll
                for (int h = 0; h < 8; ++h) { float dd = c[h][r] - mu; var += dd * dd; }
                var *= 0.125f;
                const float rs = 1.0f / sqrtf(var + 1e-5f);
                const bool keep = mok && (l < len);
                #pragma unroll
                for (int hh = 0; hh < 4; ++hh) {
                    const int h = h0 + hh;
                    float e = 0.f;
                    if (keep) {
                        float val = (c[h][r] - mu) * rs * g[h] + be[h];
                        e = __expf(val - M);
                    }
                    sum[h][r] += e;
                    se[(hh * 16 + quad * 4 + r) * LDS_PITCH + wv * 64 + mt * 16 + col] =
                        (_Float16)e;
                }
            }
        }
        __syncthreads();
        // coalesced store: 64 rows x 512 B (32 lanes x 16 B per row)
        #pragma unroll
        for (int it = 0; it < 8; ++it) {
            const int rr = it * 8 + (t >> 5);
            const int h = h0 + (rr >> 4), l = rr & 15;
            half8 v = *(half8*)&se[rr * LDS_PITCH + (t & 31) * 8];
            *(half8*)&S[((size_t)((b * 8 + h) * 1024 + lbase + l)) * 1024
                        + q * 256 + (t & 31) * 8] = v;
        }
        __syncthreads();
    }

    // reduce row partial sums over the 16 col-lanes of each quad
    #pragma unroll
    for (int h = 0; h < 8; ++h)
        #pragma unroll
        for (int r = 0; r < 4; ++r) {
            float s = sum[h][r];
            s += __shfl_xor(s, 1); s += __shfl_xor(s, 2);
            s += __shfl_xor(s, 4); s += __shfl_xor(s, 8);
            sum[h][r] = s;
        }
    if (col == 0) {
        #pragma unroll
        for (int h = 0; h < 8; ++h)
            #pragma unroll
            for (int r = 0; r < 4; ++r)
                spart[((size_t)((b * 8 + h) * 1024 + lbase + quad * 4 + r)) * 16
                      + q * 4 + wv] = sum[h][r];
    }
}

// ---------- spv: pv (blocks 0..511) and wsum (blocks 512..1023) merged into
// one dispatch. Both are independent S-readers; co-scheduling hides each
// other's memory latency and removes one graph drain boundary.
__global__ __launch_bounds__(512) void spv(
    const _Float16* __restrict__ S, const _Float16* __restrict__ Vt,
    const float* __restrict__ spart, const float* __restrict__ doc,
    float* __restrict__ out, float* __restrict__ wacc)
{
    __shared__ float smem[5248];   // pv: 64 inv + 4*64*20 comb; wsum: 64 inv + 4096
    const int t = threadIdx.x;
    const int bi = blockIdx.x;

    if (bi < 512) {
        // ----- pv: streaming PV MFMA on raw fp16 e, 8 waves.
        // Waves 0-3: l-groups for m in [0,512); waves 4-7: m in [512,1024).
        float* inv_s = smem;
        float* comb = smem + 64;           // [lg][lane][20]
        const int wv = t >> 6, lane = t & 63;
        const int col = lane & 15, quad = lane >> 4;
        const int lb = bi & 15, h = (bi >> 4) & 7, b = bi >> 7;
        const int lg = wv & 3, mh = wv >> 2;
        const int l0 = lb * 64 + lg * 16;
        const size_t rbase = (size_t)(b * 8 + h) * 1024 + lb * 64;

        if (t < 64) {
            const int len = (int)doc[b];
            float s = 0.f;
            #pragma unroll
            for (int j = 0; j < 16; ++j) s += spart[(rbase + t) * 16 + j];
            inv_s[t] = ((lb * 64 + t) < len && s > 0.f) ? 1.0f / s : 0.f;
        }

        const _Float16* Arow = S + ((size_t)(b * 8 + h) * 1024 + l0 + col) * 1024
                             + mh * 512;
        const _Float16* Vb = Vt + (size_t)(b * 8 + h) * 65536 + (size_t)col * 1024
                           + quad * 8 + mh * 512;

        floatx4 acc[4] = {{0,0,0,0},{0,0,0,0},{0,0,0,0},{0,0,0,0}};

        half8 ebuf[8];
        #pragma unroll
        for (int i = 0; i < 8; ++i)
            ebuf[i] = *(const half8*)&Arow[i * 32 + quad * 8];

        half8 va[4], vb[4];
        #pragma unroll
        for (int dt = 0; dt < 4; ++dt)
            va[dt] = *(const half8*)&Vb[(size_t)(dt * 16) * 1024];

        #pragma unroll
        for (int kc = 0; kc < 16; kc += 2) {
            half8 ae = ebuf[kc & 7];
            if (kc + 8 < 16)
                ebuf[kc & 7] = *(const half8*)&Arow[(kc + 8) * 32 + quad * 8];
            #pragma unroll
            for (int dt = 0; dt < 4; ++dt)
                vb[dt] = *(const half8*)&Vb[(size_t)(dt * 16) * 1024 + (kc + 1) * 32];
            #pragma unroll
            for (int dt = 0; dt < 4; ++dt)
                acc[dt] = __builtin_amdgcn_mfma_f32_16x16x32_f16(ae, va[dt], acc[dt], 0, 0, 0);

            half8 ao = ebuf[(kc + 1) & 7];
            if (kc + 9 < 16)
                ebuf[(kc + 1) & 7] = *(const half8*)&Arow[(kc + 9) * 32 + quad * 8];
            if (kc + 2 < 16) {
                #pragma unroll
                for (int dt = 0; dt < 4; ++dt)
                    va[dt] = *(const half8*)&Vb[(size_t)(dt * 16) * 1024 + (kc + 2) * 32];
            }
            #pragma unroll
            for (int dt = 0; dt < 4; ++dt)
                acc[dt] = __builtin_amdgcn_mfma_f32_16x16x32_f16(ao, vb[dt], acc[dt], 0, 0, 0);
        }

        if (mh == 1) {
            #pragma unroll
            for (int dt = 0; dt < 4; ++dt)
                *(floatx4*)&comb[(lg * 64 + lane) * 20 + dt * 4] = acc[dt];
        }
        __syncthreads();
        if (mh == 0) {
            #pragma unroll
            for (int dt = 0; dt < 4; ++dt)
                acc[dt] += *(floatx4*)&comb[(lg * 64 + lane) * 20 + dt * 4];
            #pragma unroll
            for (int r = 0; r < 4; ++r) {
                const int l = l0 + quad * 4 + r;
                const float ivr = inv_s[lg * 16 + quad * 4 + r];
                float* orow = out + (size_t)(b * 1024 + l) * 512 + h * 64;
                #pragma unroll
                for (int dt = 0; dt < 4; ++dt)
                    orow[dt * 16 + col] = acc[dt][r] * ivr;
            }
        }
    } else {
        // ----- wsum: w column sums, m-major ownership, 16B loads,
        // 4 l-parities combined through LDS, 4 atomics per thread (t<256).
        float* inv_s = smem;
        float* ws = smem + 64;             // [4][1024]
        const int bj = bi - 512;           // 512 = 4b x 8h x 16 slab(64 l)
        const int lc = bj & 15, h = (bj >> 4) & 7, b = bj >> 7;
        const size_t rbase = (size_t)(b * 8 + h) * 1024 + lc * 64;

        if (t < 64) {
            const int len = (int)doc[b];
            float s = 0.f;
            #pragma unroll
            for (int j = 0; j < 16; ++j) s += spart[(rbase + t) * 16 + j];
            inv_s[t] = ((lc * 64 + t) < len && s > 0.f) ? 1.0f / s : 0.f;
        }
        __syncthreads();

        const _Float16* Sb = S + rbase * 1024;
        const int mi = (t & 127) * 8;
        const int lp = t >> 7;

        float acc[8];
        #pragma unroll
        for (int j = 0; j < 8; ++j) acc[j] = 0.f;

        #pragma unroll 4
        for (int l = lp; l < 64; l += 4) {
            const float iv = inv_s[l];
            half8 e = *(const half8*)&Sb[(size_t)l * 1024 + mi];
            #pragma unroll
            for (int j = 0; j < 8; ++j) acc[j] += (float)e[j] * iv;
        }

        #pragma unroll
        for (int j = 0; j < 8; ++j) ws[lp * 1024 + mi + j] = acc[j];
        __syncthreads();

        if (t < 256) {
            float* wb = wacc + b * 1024;
            #pragma unroll
            for (int i = 0; i < 4; ++i) {
                const int m = t * 4 + i;
                atomicAdd(&wb[m], ws[m] + ws[1024 + m] + ws[2048 + m] + ws[3072 + m]);
            }
        }
    }
}

// ---------- w finalize: w = softmax_m( (wacc/8)/len ), invalid -> 0
__global__ __launch_bounds__(256) void w_final(
    const float* __restrict__ wacc, const float* __restrict__ doc,
    float* __restrict__ wout)
{
    const int b = blockIdx.x;
    const int t = threadIdx.x;
    __shared__ float red[4];

    const float ds = doc[b];
    const int len = (int)ds;

    float v[4];
    float mx = -INFINITY;
    #pragma unroll
    for (int i = 0; i < 4; ++i) {
        const int m = t + 256 * i;
        const float raw = wacc[b * L_ + m];
        v[i] = (m < len) ? (raw * 0.125f) / ds : -INFINITY;
        mx = fmaxf(mx, v[i]);
    }
    #pragma unroll
    for (int off = 1; off < 64; off <<= 1) mx = fmaxf(mx, __shfl_xor(mx, off));
    if ((t & 63) == 0) red[t >> 6] = mx;
    __syncthreads();
    mx = fmaxf(fmaxf(red[0], red[1]), fmaxf(red[2], red[3]));

    float e[4];
    float sm = 0.f;
    #pragma unroll
    for (int i = 0; i < 4; ++i) {
        e[i] = (v[i] != -INFINITY) ? __expf(v[i] - mx) : 0.f;
        sm += e[i];
    }
    #pragma unroll
    for (int off = 1; off < 64; off <<= 1) sm += __shfl_xor(sm, off);
    __syncthreads();
    if ((t & 63) == 0) red[t >> 6] = sm;
    __syncthreads();
    sm = red[0] + red[1] + red[2] + red[3];
    const float inv = (sm > 0.f) ? 1.0f / sm : 0.f;

    #pragma unroll
    for (int i = 0; i < 4; ++i)
        wout[b * L_ + t + 256 * i] = e[i] * inv;
}

extern "C" void kernel_launch(void* const* d_in, const int* in_sizes, int n_in,
                              void* d_out, int out_size, void* d_ws, size_t ws_size,
                              hipStream_t stream)
{
    const float* K     = (const float*)d_in[0];
    const float* Q     = (const float*)d_in[1];
    const float* V     = (const float*)d_in[2];
    const float* doc   = (const float*)d_in[3];
    const float* gamma = (const float*)d_in[4];
    const float* beta  = (const float*)d_in[5];

    float* out  = (float*)d_out;
    float* wout = out + (size_t)4 * L_ * D_;

    _Float16* S    = (_Float16*)d_ws;               // 64 MB (e-values, flat)
    _Float16* K16  = S + (size_t)33554432;          // +4 MB
    _Float16* Q16  = K16 + 2097152;                 // +4 MB
    _Float16* Vt   = Q16 + 2097152;                 // +4 MB
    float*    spart = (float*)(Vt + 2097152);       // 2 MB (32768 x 16)
    float*    wacc  = spart + 524288 + 32768;       // 16 KB

    hipMemsetAsync(wacc, 0, 4096 * sizeof(float), stream);
    prep   <<<dim3(2560), dim3(256), 0, stream>>>(K, Q, V, K16, Q16, Vt);
    qk_ln  <<<dim3(1024), dim3(256), 0, stream>>>(K16, Q16, gamma, beta, doc, S, spart);
    spv    <<<dim3(1024), dim3(512), 0, stream>>>(S, Vt, spart, doc, out, wacc);
    w_final<<<dim3(4),    dim3(256), 0, stream>>>(wacc, doc, wout);
}

// Round 8
// 190.726 us; speedup vs baseline: 1.3907x; 1.3907x over previous
//
#include <hip/hip_runtime.h>
#include <math.h>

// B=4, L=1024, D=512, H=8, d=64
#define L_ 1024
#define D_ 512

typedef _Float16 half8 __attribute__((ext_vector_type(8)));
typedef _Float16 half4v __attribute__((ext_vector_type(4)));
typedef _Float16 half2v __attribute__((ext_vector_type(2)));
typedef float floatx4 __attribute__((ext_vector_type(4)));

#define LDS_PITCH 264   // halves per (h,l) row in qk_ln staging (16B-aligned, bank-skewed)

// ---------- prep: K,Q -> fp16 straight; V -> fp16 transposed Vt[b][h][d][m]
// (round-0 proven form)
__global__ __launch_bounds__(256) void prep(
    const float* __restrict__ K, const float* __restrict__ Q,
    const float* __restrict__ V,
    _Float16* __restrict__ K16, _Float16* __restrict__ Q16,
    _Float16* __restrict__ Vt)
{
    __shared__ _Float16 tile[64][72];
    const int t = threadIdx.x;
    const int bi = blockIdx.x;
    if (bi < 256) {
        for (int it = 0; it < 16; ++it) {
            size_t f = (size_t)bi * 4096 + it * 256 + t;
            const float4* src; _Float16* dst;
            if (f < 524288) { src = (const float4*)K; dst = K16; }
            else            { src = (const float4*)Q; dst = Q16; f -= 524288; }
            float4 v = src[f];
            half4v h = { (_Float16)v.x, (_Float16)v.y, (_Float16)v.z, (_Float16)v.w };
            *(half4v*)&dst[f * 4] = h;
        }
    } else {
        const int id = bi - 256;            // 512 blocks: 4b x 8h x 16 mtiles
        const int mt = id & 15, h = (id >> 4) & 7, b = id >> 7;
        const float4* Vf4 = (const float4*)V;
        for (int it = 0; it < 4; ++it) {
            const int ml = (t >> 4) + 16 * it;
            const int c4 = t & 15;
            float4 v = Vf4[(size_t)(b * 1024 + mt * 64 + ml) * 128 + h * 16 + c4];
            tile[c4 * 4 + 0][ml] = (_Float16)v.x;
            tile[c4 * 4 + 1][ml] = (_Float16)v.y;
            tile[c4 * 4 + 2][ml] = (_Float16)v.z;
            tile[c4 * 4 + 3][ml] = (_Float16)v.w;
        }
        __syncthreads();
        const int d = t >> 2, seg = t & 3;
        half8 o0 = *(half8*)&tile[d][seg * 16];
        half8 o1 = *(half8*)&tile[d][seg * 16 + 8];
        size_t obase = ((size_t)(b * 8 + h) * 64 + d) * 1024 + mt * 64 + seg * 16;
        *(half8*)&Vt[obase] = o0;
        *(half8*)&Vt[obase + 8] = o1;
    }
}

// ---------- qk_ln: e = exp(LN(K.Q^T) - M) via fp16 MFMA, masked, stored
// coalesced to S[b][h][l][m] via LDS; per-row partial sums -> spart.
// (round-0 proven configuration: ~54 us, 0 bank conflicts.)
// M = max_h(2.8285*|gamma_h|+|beta_h|) is a data-independent LN output bound,
// so no per-row max pass is needed (exp never overflows).
__global__ __launch_bounds__(256) void qk_ln(
    const _Float16* __restrict__ K16, const _Float16* __restrict__ Q16,
    const float* __restrict__ gamma, const float* __restrict__ beta,
    const float* __restrict__ doc,
    _Float16* __restrict__ S, float* __restrict__ spart)
{
    __shared__ _Float16 se[8 * 16 * LDS_PITCH];   // 67584 B -> 2 blocks/CU

    const int t  = threadIdx.x;
    const int bi = blockIdx.x;              // 1024 = 4b x 64 lt x 4 q
    const int b  = bi & 3;
    const int lt = (bi >> 2) & 63;
    const int q  = bi >> 8;
    const int wv = t >> 6, lane = t & 63;
    const int col = lane & 15, quad = lane >> 4;
    const int len = (int)doc[b];
    const int lbase = lt * 16;

    float g[8], be[8], M = 0.f;
    #pragma unroll
    for (int h = 0; h < 8; ++h) {
        g[h] = gamma[h]; be[h] = beta[h];
        M = fmaxf(M, 2.8285f * fabsf(g[h]) + fabsf(be[h]));
    }

    const _Float16* Kb = K16 + (size_t)b * 524288;
    const _Float16* Qb = Q16 + (size_t)b * 524288;
    const size_t krow = (size_t)(lbase + col) * 512;

    half8 a0[8], a1[8];
    #pragma unroll
    for (int h = 0; h < 8; ++h) {
        a0[h] = *(const half8*)&Kb[krow + h * 64 + quad * 8];
        a1[h] = *(const half8*)&Kb[krow + h * 64 + 32 + quad * 8];
    }

    float sum[8][4];
    #pragma unroll
    for (int h = 0; h < 8; ++h)
        #pragma unroll
        for (int r = 0; r < 4; ++r) sum[h][r] = 0.f;

    for (int mt = 0; mt < 4; ++mt) {
        const int m0 = q * 256 + wv * 64 + mt * 16;
        const size_t qrow = (size_t)(m0 + col) * 512;
        floatx4 c[8];
        #pragma unroll
        for (int h = 0; h < 8; ++h) {
            half8 b0 = *(const half8*)&Qb[qrow + h * 64 + quad * 8];
            half8 b1 = *(const half8*)&Qb[qrow + h * 64 + 32 + quad * 8];
            floatx4 z = {0.f, 0.f, 0.f, 0.f};
            z    = __builtin_amdgcn_mfma_f32_16x16x32_f16(a0[h], b0, z, 0, 0, 0);
            c[h] = __builtin_amdgcn_mfma_f32_16x16x32_f16(a1[h], b1, z, 0, 0, 0);
        }
        const bool mok = (m0 + col) < len;
        #pragma unroll
        for (int r = 0; r < 4; ++r) {
            const int l = lbase + quad * 4 + r;
            float mu = 0.f;
            #pragma unroll
            for (int h = 0; h < 8; ++h) mu += c[h][r];
            mu *= 0.125f;
            float var = 0.f;
            #pragma unroll
            for (int h = 0; h < 8; ++h) { float dd = c[h][r] - mu; var += dd * dd; }
            var *= 0.125f;
            const float rs = 1.0f / sqrtf(var + 1e-5f);
            const bool keep = mok && (l < len);
            #pragma unroll
            for (int h = 0; h < 8; ++h) {
                float e = 0.f;
                if (keep) {
                    float val = (c[h][r] - mu) * rs * g[h] + be[h];
                    e = __expf(val - M);
                }
                sum[h][r] += e;
                se[(h * 16 + quad * 4 + r) * LDS_PITCH + wv * 64 + mt * 16 + col] =
                    (_Float16)e;
            }
        }
    }

    // reduce row partial sums over the 16 col-lanes of each quad
    #pragma unroll
    for (int h = 0; h < 8; ++h)
        #pragma unroll
        for (int r = 0; r < 4; ++r) {
            float s = sum[h][r];
            s += __shfl_xor(s, 1); s += __shfl_xor(s, 2);
            s += __shfl_xor(s, 4); s += __shfl_xor(s, 8);
            sum[h][r] = s;
        }
    if (col == 0) {
        #pragma unroll
        for (int h = 0; h < 8; ++h)
            #pragma unroll
            for (int r = 0; r < 4; ++r)
                spart[((size_t)((b * 8 + h) * 1024 + lbase + quad * 4 + r)) * 16
                      + q * 4 + wv] = sum[h][r];
    }
    __syncthreads();

    // coalesced store: 128 rows x 512 B
    for (int it = 0; it < 16; ++it) {
        const int rr = it * 8 + (t >> 5);
        const int h = rr >> 4, l = rr & 15;
        half8 v = *(half8*)&se[rr * LDS_PITCH + (t & 31) * 8];
        *(half8*)&S[((size_t)((b * 8 + h) * 1024 + lbase + l)) * 1024
                    + q * 256 + (t & 31) * 8] = v;
    }
}

// ---------- pv: round-0 fused PV + colsum structure, upgraded with the three
// validated deltas: (1) 8 waves / m-split -> 2x occupancy and HALF the serial
// colsum chain per wave (16 kc not 32); (2) 8-deep e-ring + Vt ping-pong
// prefetch -> loads stream; (3) inline inv from spart (identical summation
// order to the deleted stats_reduce -> bitwise-identical inv).
// p = e*inv feeds both the MFMA (so epilogue stores acc directly) and the
// packed-fp16 shuffle-tree colsum (round-0 numerics).
__global__ __launch_bounds__(512) void pv(
    const _Float16* __restrict__ S, const _Float16* __restrict__ Vt,
    const float* __restrict__ spart, const float* __restrict__ doc,
    float* __restrict__ out, float* __restrict__ wacc)
{
    __shared__ float inv_s[64];
    __shared__ float cs[1024];
    __shared__ float comb[4][64][20];

    const int t = threadIdx.x, wv = t >> 6, lane = t & 63;
    const int col = lane & 15, quad = lane >> 4;
    const int bi = blockIdx.x;            // 512 = 4b x 8h x 16 lb
    const int lb = bi & 15, h = (bi >> 4) & 7, b = bi >> 7;
    const int lg = wv & 3, mh = wv >> 2;
    const int l0 = lb * 64 + lg * 16;
    const size_t rbase = (size_t)(b * 8 + h) * 1024 + lb * 64;

    cs[t] = 0.f; cs[t + 512] = 0.f;
    if (t < 64) {
        const int len = (int)doc[b];
        float s = 0.f;
        #pragma unroll
        for (int j = 0; j < 16; ++j) s += spart[(rbase + t) * 16 + j];
        inv_s[t] = ((lb * 64 + t) < len && s > 0.f) ? 1.0f / s : 0.f;
    }
    __syncthreads();

    const float inv = inv_s[lg * 16 + col];

    const _Float16* Arow = S + ((size_t)(b * 8 + h) * 1024 + l0 + col) * 1024
                         + mh * 512;
    const _Float16* Vb = Vt + (size_t)(b * 8 + h) * 65536 + (size_t)col * 1024
                       + quad * 8 + mh * 512;

    floatx4 acc[4] = {{0,0,0,0},{0,0,0,0},{0,0,0,0},{0,0,0,0}};

    half8 ebuf[8];
    #pragma unroll
    for (int i = 0; i < 8; ++i)
        ebuf[i] = *(const half8*)&Arow[i * 32 + quad * 8];

    half8 va[4], vb2[4];
    #pragma unroll
    for (int dt = 0; dt < 4; ++dt)
        va[dt] = *(const half8*)&Vb[(size_t)(dt * 16) * 1024];

    #pragma unroll
    for (int kc = 0; kc < 16; kc += 2) {
        // ---- even step: consume va, prefetch vb2 (kc+1)
        half8 e0 = ebuf[kc & 7];
        if (kc + 8 < 16)
            ebuf[kc & 7] = *(const half8*)&Arow[(kc + 8) * 32 + quad * 8];
        #pragma unroll
        for (int dt = 0; dt < 4; ++dt)
            vb2[dt] = *(const half8*)&Vb[(size_t)(dt * 16) * 1024 + (kc + 1) * 32];

        half8 a;
        #pragma unroll
        for (int j = 0; j < 8; ++j) a[j] = (_Float16)((float)e0[j] * inv);
        {
            const int mbase = mh * 512 + kc * 32 + quad * 8;
            #pragma unroll
            for (int u = 0; u < 4; ++u) {
                half2v p2 = { a[2 * u], a[2 * u + 1] };
                int bits = *(int*)&p2;
                #pragma unroll
                for (int o = 1; o < 16; o <<= 1) {
                    int ob = __shfl_xor(bits, o);
                    half2v po = *(half2v*)&ob;
                    half2v pc = *(half2v*)&bits;
                    pc[0] = pc[0] + po[0]; pc[1] = pc[1] + po[1];
                    bits = *(int*)&pc;
                }
                if (col == 0) {
                    half2v pc = *(half2v*)&bits;
                    atomicAdd(&cs[mbase + 2 * u],     (float)pc[0]);
                    atomicAdd(&cs[mbase + 2 * u + 1], (float)pc[1]);
                }
            }
        }
        #pragma unroll
        for (int dt = 0; dt < 4; ++dt)
            acc[dt] = __builtin_amdgcn_mfma_f32_16x16x32_f16(a, va[dt], acc[dt], 0, 0, 0);

        // ---- odd step: consume vb2, prefetch va (kc+2)
        half8 e1 = ebuf[(kc + 1) & 7];
        if (kc + 9 < 16)
            ebuf[(kc + 1) & 7] = *(const half8*)&Arow[(kc + 9) * 32 + quad * 8];
        if (kc + 2 < 16) {
            #pragma unroll
            for (int dt = 0; dt < 4; ++dt)
                va[dt] = *(const half8*)&Vb[(size_t)(dt * 16) * 1024 + (kc + 2) * 32];
        }

        half8 a2;
        #pragma unroll
        for (int j = 0; j < 8; ++j) a2[j] = (_Float16)((float)e1[j] * inv);
        {
            const int mbase = mh * 512 + (kc + 1) * 32 + quad * 8;
            #pragma unroll
            for (int u = 0; u < 4; ++u) {
                half2v p2 = { a2[2 * u], a2[2 * u + 1] };
                int bits = *(int*)&p2;
                #pragma unroll
                for (int o = 1; o < 16; o <<= 1) {
                    int ob = __shfl_xor(bits, o);
                    half2v po = *(half2v*)&ob;
                    half2v pc = *(half2v*)&bits;
                    pc[0] = pc[0] + po[0]; pc[1] = pc[1] + po[1];
                    bits = *(int*)&pc;
                }
                if (col == 0) {
                    half2v pc = *(half2v*)&bits;
                    atomicAdd(&cs[mbase + 2 * u],     (float)pc[0]);
                    atomicAdd(&cs[mbase + 2 * u + 1], (float)pc[1]);
                }
            }
        }
        #pragma unroll
        for (int dt = 0; dt < 4; ++dt)
            acc[dt] = __builtin_amdgcn_mfma_f32_16x16x32_f16(a2, vb2[dt], acc[dt], 0, 0, 0);
    }

    if (mh == 1) {
        #pragma unroll
        for (int dt = 0; dt < 4; ++dt)
            *(floatx4*)&comb[lg][lane][dt * 4] = acc[dt];
    }
    __syncthreads();   // covers comb writes AND all cs atomics
    if (mh == 0) {
        #pragma unroll
        for (int dt = 0; dt < 4; ++dt)
            acc[dt] += *(floatx4*)&comb[lg][lane][dt * 4];
        #pragma unroll
        for (int r = 0; r < 4; ++r) {
            const int l = l0 + quad * 4 + r;
            float* orow = out + (size_t)(b * 1024 + l) * 512 + h * 64;
            #pragma unroll
            for (int dt = 0; dt < 4; ++dt)
                orow[dt * 16 + col] = acc[dt][r];
        }
    }
    atomicAdd(&wacc[b * 1024 + t],       cs[t]);
    atomicAdd(&wacc[b * 1024 + t + 512], cs[t + 512]);
}

// ---------- w finalize: w = softmax_m( (wacc/8)/len ), invalid -> 0
__global__ __launch_bounds__(256) void w_final(
    const float* __restrict__ wacc, const float* __restrict__ doc,
    float* __restrict__ wout)
{
    const int b = blockIdx.x;
    const int t = threadIdx.x;
    __shared__ float red[4];

    const float ds = doc[b];
    const int len = (int)ds;

    float v[4];
    float mx = -INFINITY;
    #pragma unroll
    for (int i = 0; i < 4; ++i) {
        const int m = t + 256 * i;
        const float raw = wacc[b * L_ + m];
        v[i] = (m < len) ? (raw * 0.125f) / ds : -INFINITY;
        mx = fmaxf(mx, v[i]);
    }
    #pragma unroll
    for (int off = 1; off < 64; off <<= 1) mx = fmaxf(mx, __shfl_xor(mx, off));
    if ((t & 63) == 0) red[t >> 6] = mx;
    __syncthreads();
    mx = fmaxf(fmaxf(red[0], red[1]), fmaxf(red[2], red[3]));

    float e[4];
    float sm = 0.f;
    #pragma unroll
    for (int i = 0; i < 4; ++i) {
        e[i] = (v[i] != -INFINITY) ? __expf(v[i] - mx) : 0.f;
        sm += e[i];
    }
    #pragma unroll
    for (int off = 1; off < 64; off <<= 1) sm += __shfl_xor(sm, off);
    __syncthreads();
    if ((t & 63) == 0) red[t >> 6] = sm;
    __syncthreads();
    sm = red[0] + red[1] + red[2] + red[3];
    const float inv = (sm > 0.f) ? 1.0f / sm : 0.f;

    #pragma unroll
    for (int i = 0; i < 4; ++i)
        wout[b * L_ + t + 256 * i] = e[i] * inv;
}

extern "C" void kernel_launch(void* const* d_in, const int* in_sizes, int n_in,
                              void* d_out, int out_size, void* d_ws, size_t ws_size,
                              hipStream_t stream)
{
    const float* K     = (const float*)d_in[0];
    const float* Q     = (const float*)d_in[1];
    const float* V     = (const float*)d_in[2];
    const float* doc   = (const float*)d_in[3];
    const float* gamma = (const float*)d_in[4];
    const float* beta  = (const float*)d_in[5];

    float* out  = (float*)d_out;
    float* wout = out + (size_t)4 * L_ * D_;

    _Float16* S    = (_Float16*)d_ws;               // 64 MB (e-values, flat)
    _Float16* K16  = S + (size_t)33554432;          // +4 MB
    _Float16* Q16  = K16 + 2097152;                 // +4 MB
    _Float16* Vt   = Q16 + 2097152;                 // +4 MB
    float*    spart = (float*)(Vt + 2097152);       // 2 MB (32768 x 16)
    float*    wacc  = spart + 524288 + 32768;       // 16 KB

    hipMemsetAsync(wacc, 0, 4096 * sizeof(float), stream);
    prep   <<<dim3(768),  dim3(256), 0, stream>>>(K, Q, V, K16, Q16, Vt);
    qk_ln  <<<dim3(1024), dim3(256), 0, stream>>>(K16, Q16, gamma, beta, doc, S, spart);
    pv     <<<dim3(512),  dim3(512), 0, stream>>>(S, Vt, spart, doc, out, wacc);
    w_final<<<dim3(4),    dim3(256), 0, stream>>>(wacc, doc, wout);
}

// Round 9
// 189.743 us; speedup vs baseline: 1.3979x; 1.0052x over previous
//
#include <hip/hip_runtime.h>
#include <math.h>

// B=4, L=1024, D=512, H=8, d=64
#define L_ 1024
#define D_ 512

typedef _Float16 half8 __attribute__((ext_vector_type(8)));
typedef _Float16 half4v __attribute__((ext_vector_type(4)));
typedef _Float16 half2v __attribute__((ext_vector_type(2)));
typedef float floatx4 __attribute__((ext_vector_type(4)));

#define LDS_PITCH 264   // halves per (h,l) row in qk_ln staging (16B-aligned, bank-skewed)

// ---------- prep: K,Q -> fp16 straight; V -> fp16 transposed Vt[b][h][d][m]
// K/Q section: 2048 blocks x 2 iters (8 blocks/CU, proven r5/r6) instead of
// the 1-block/CU round-0 form.
__global__ __launch_bounds__(256) void prep(
    const float* __restrict__ K, const float* __restrict__ Q,
    const float* __restrict__ V,
    _Float16* __restrict__ K16, _Float16* __restrict__ Q16,
    _Float16* __restrict__ Vt)
{
    __shared__ _Float16 tile[64][72];
    const int t = threadIdx.x;
    const int bi = blockIdx.x;
    if (bi < 2048) {
        #pragma unroll
        for (int it = 0; it < 2; ++it) {
            size_t f = (size_t)bi * 512 + it * 256 + t;
            const float4* src; _Float16* dst;
            if (f < 524288) { src = (const float4*)K; dst = K16; }
            else            { src = (const float4*)Q; dst = Q16; f -= 524288; }
            float4 v = src[f];
            half4v h = { (_Float16)v.x, (_Float16)v.y, (_Float16)v.z, (_Float16)v.w };
            *(half4v*)&dst[f * 4] = h;
        }
    } else {
        const int id = bi - 2048;           // 512 blocks: 4b x 8h x 16 mtiles
        const int mt = id & 15, h = (id >> 4) & 7, b = id >> 7;
        const float4* Vf4 = (const float4*)V;
        for (int it = 0; it < 4; ++it) {
            const int ml = (t >> 4) + 16 * it;
            const int c4 = t & 15;
            float4 v = Vf4[(size_t)(b * 1024 + mt * 64 + ml) * 128 + h * 16 + c4];
            tile[c4 * 4 + 0][ml] = (_Float16)v.x;
            tile[c4 * 4 + 1][ml] = (_Float16)v.y;
            tile[c4 * 4 + 2][ml] = (_Float16)v.z;
            tile[c4 * 4 + 3][ml] = (_Float16)v.w;
        }
        __syncthreads();
        const int d = t >> 2, seg = t & 3;
        half8 o0 = *(half8*)&tile[d][seg * 16];
        half8 o1 = *(half8*)&tile[d][seg * 16 + 8];
        size_t obase = ((size_t)(b * 8 + h) * 64 + d) * 1024 + mt * 64 + seg * 16;
        *(half8*)&Vt[obase] = o0;
        *(half8*)&Vt[obase + 8] = o1;
    }
}

// ---------- qk_ln: e = exp(LN(K.Q^T) - M) via fp16 MFMA, masked, stored
// coalesced to S[b][h][l][m] via LDS; per-row partial sums -> spart.
// (round-0 proven configuration, byte-identical.)
// M = max_h(2.8285*|gamma_h|+|beta_h|) is a data-independent LN output bound,
// so no per-row max pass is needed (exp never overflows).
__global__ __launch_bounds__(256) void qk_ln(
    const _Float16* __restrict__ K16, const _Float16* __restrict__ Q16,
    const float* __restrict__ gamma, const float* __restrict__ beta,
    const float* __restrict__ doc,
    _Float16* __restrict__ S, float* __restrict__ spart)
{
    __shared__ _Float16 se[8 * 16 * LDS_PITCH];   // 67584 B -> 2 blocks/CU

    const int t  = threadIdx.x;
    const int bi = blockIdx.x;              // 1024 = 4b x 64 lt x 4 q
    const int b  = bi & 3;
    const int lt = (bi >> 2) & 63;
    const int q  = bi >> 8;
    const int wv = t >> 6, lane = t & 63;
    const int col = lane & 15, quad = lane >> 4;
    const int len = (int)doc[b];
    const int lbase = lt * 16;

    float g[8], be[8], M = 0.f;
    #pragma unroll
    for (int h = 0; h < 8; ++h) {
        g[h] = gamma[h]; be[h] = beta[h];
        M = fmaxf(M, 2.8285f * fabsf(g[h]) + fabsf(be[h]));
    }

    const _Float16* Kb = K16 + (size_t)b * 524288;
    const _Float16* Qb = Q16 + (size_t)b * 524288;
    const size_t krow = (size_t)(lbase + col) * 512;

    half8 a0[8], a1[8];
    #pragma unroll
    for (int h = 0; h < 8; ++h) {
        a0[h] = *(const half8*)&Kb[krow + h * 64 + quad * 8];
        a1[h] = *(const half8*)&Kb[krow + h * 64 + 32 + quad * 8];
    }

    float sum[8][4];
    #pragma unroll
    for (int h = 0; h < 8; ++h)
        #pragma unroll
        for (int r = 0; r < 4; ++r) sum[h][r] = 0.f;

    for (int mt = 0; mt < 4; ++mt) {
        const int m0 = q * 256 + wv * 64 + mt * 16;
        const size_t qrow = (size_t)(m0 + col) * 512;
        floatx4 c[8];
        #pragma unroll
        for (int h = 0; h < 8; ++h) {
            half8 b0 = *(const half8*)&Qb[qrow + h * 64 + quad * 8];
            half8 b1 = *(const half8*)&Qb[qrow + h * 64 + 32 + quad * 8];
            floatx4 z = {0.f, 0.f, 0.f, 0.f};
            z    = __builtin_amdgcn_mfma_f32_16x16x32_f16(a0[h], b0, z, 0, 0, 0);
            c[h] = __builtin_amdgcn_mfma_f32_16x16x32_f16(a1[h], b1, z, 0, 0, 0);
        }
        const bool mok = (m0 + col) < len;
        #pragma unroll
        for (int r = 0; r < 4; ++r) {
            const int l = lbase + quad * 4 + r;
            float mu = 0.f;
            #pragma unroll
            for (int h = 0; h < 8; ++h) mu += c[h][r];
            mu *= 0.125f;
            float var = 0.f;
            #pragma unroll
            for (int h = 0; h < 8; ++h) { float dd = c[h][r] - mu; var += dd * dd; }
            var *= 0.125f;
            const float rs = 1.0f / sqrtf(var + 1e-5f);
            const bool keep = mok && (l < len);
            #pragma unroll
            for (int h = 0; h < 8; ++h) {
                float e = 0.f;
                if (keep) {
                    float val = (c[h][r] - mu) * rs * g[h] + be[h];
                    e = __expf(val - M);
                }
                sum[h][r] += e;
                se[(h * 16 + quad * 4 + r) * LDS_PITCH + wv * 64 + mt * 16 + col] =
                    (_Float16)e;
            }
        }
    }

    // reduce row partial sums over the 16 col-lanes of each quad
    #pragma unroll
    for (int h = 0; h < 8; ++h)
        #pragma unroll
        for (int r = 0; r < 4; ++r) {
            float s = sum[h][r];
            s += __shfl_xor(s, 1); s += __shfl_xor(s, 2);
            s += __shfl_xor(s, 4); s += __shfl_xor(s, 8);
            sum[h][r] = s;
        }
    if (col == 0) {
        #pragma unroll
        for (int h = 0; h < 8; ++h)
            #pragma unroll
            for (int r = 0; r < 4; ++r)
                spart[((size_t)((b * 8 + h) * 1024 + lbase + quad * 4 + r)) * 16
                      + q * 4 + wv] = sum[h][r];
    }
    __syncthreads();

    // coalesced store: 128 rows x 512 B
    for (int it = 0; it < 16; ++it) {
        const int rr = it * 8 + (t >> 5);
        const int h = rr >> 4, l = rr & 15;
        half8 v = *(half8*)&se[rr * LDS_PITCH + (t & 31) * 8];
        *(half8*)&S[((size_t)((b * 8 + h) * 1024 + lbase + l)) * 1024
                    + q * 256 + (t & 31) * 8] = v;
    }
}

// ---------- pv: fused PV + colsum (round-8 best), with the MFMA chain
// DECOUPLED from the colsum chain: MFMA consumes raw fp16 e straight from
// the load (fp32 accumulate; inv applied once in the epilogue — round-1
// proven numerics), while the scaled p = e*inv feeds only the packed-fp16
// shuffle-tree colsum. The two chains run on different pipes (MFMA/VMEM vs
// VALU/DS) and overlap. 8 waves: lg = l-group, mh = m-half; 8-deep e-ring +
// Vt ping-pong prefetch; inline inv from spart (bitwise-identical to the
// deleted stats_reduce).
__global__ __launch_bounds__(512) void pv(
    const _Float16* __restrict__ S, const _Float16* __restrict__ Vt,
    const float* __restrict__ spart, const float* __restrict__ doc,
    float* __restrict__ out, float* __restrict__ wacc)
{
    __shared__ float inv_s[64];
    __shared__ float cs[1024];
    __shared__ float comb[4][64][20];

    const int t = threadIdx.x, wv = t >> 6, lane = t & 63;
    const int col = lane & 15, quad = lane >> 4;
    const int bi = blockIdx.x;            // 512 = 4b x 8h x 16 lb
    const int lb = bi & 15, h = (bi >> 4) & 7, b = bi >> 7;
    const int lg = wv & 3, mh = wv >> 2;
    const int l0 = lb * 64 + lg * 16;
    const size_t rbase = (size_t)(b * 8 + h) * 1024 + lb * 64;

    cs[t] = 0.f; cs[t + 512] = 0.f;
    if (t < 64) {
        const int len = (int)doc[b];
        float s = 0.f;
        #pragma unroll
        for (int j = 0; j < 16; ++j) s += spart[(rbase + t) * 16 + j];
        inv_s[t] = ((lb * 64 + t) < len && s > 0.f) ? 1.0f / s : 0.f;
    }
    __syncthreads();

    const float inv = inv_s[lg * 16 + col];

    const _Float16* Arow = S + ((size_t)(b * 8 + h) * 1024 + l0 + col) * 1024
                         + mh * 512;
    const _Float16* Vb = Vt + (size_t)(b * 8 + h) * 65536 + (size_t)col * 1024
                       + quad * 8 + mh * 512;

    floatx4 acc[4] = {{0,0,0,0},{0,0,0,0},{0,0,0,0},{0,0,0,0}};

    half8 ebuf[8];
    #pragma unroll
    for (int i = 0; i < 8; ++i)
        ebuf[i] = *(const half8*)&Arow[i * 32 + quad * 8];

    half8 va[4], vb2[4];
    #pragma unroll
    for (int dt = 0; dt < 4; ++dt)
        va[dt] = *(const half8*)&Vb[(size_t)(dt * 16) * 1024];

    #pragma unroll
    for (int kc = 0; kc < 16; kc += 2) {
        // ---- even step: consume va, prefetch vb2 (kc+1)
        half8 e0 = ebuf[kc & 7];
        if (kc + 8 < 16)
            ebuf[kc & 7] = *(const half8*)&Arow[(kc + 8) * 32 + quad * 8];
        #pragma unroll
        for (int dt = 0; dt < 4; ++dt)
            vb2[dt] = *(const half8*)&Vb[(size_t)(dt * 16) * 1024 + (kc + 1) * 32];

        // MFMA path: raw e, no VALU in between
        #pragma unroll
        for (int dt = 0; dt < 4; ++dt)
            acc[dt] = __builtin_amdgcn_mfma_f32_16x16x32_f16(e0, va[dt], acc[dt], 0, 0, 0);

        // colsum path: scaled p, shuffle-tree over the 16 l-lanes
        {
            half8 a;
            #pragma unroll
            for (int j = 0; j < 8; ++j) a[j] = (_Float16)((float)e0[j] * inv);
            const int mbase = mh * 512 + kc * 32 + quad * 8;
            #pragma unroll
            for (int u = 0; u < 4; ++u) {
                half2v p2 = { a[2 * u], a[2 * u + 1] };
                int bits = *(int*)&p2;
                #pragma unroll
                for (int o = 1; o < 16; o <<= 1) {
                    int ob = __shfl_xor(bits, o);
                    half2v po = *(half2v*)&ob;
                    half2v pc = *(half2v*)&bits;
                    pc[0] = pc[0] + po[0]; pc[1] = pc[1] + po[1];
                    bits = *(int*)&pc;
                }
                if (col == 0) {
                    half2v pc = *(half2v*)&bits;
                    atomicAdd(&cs[mbase + 2 * u],     (float)pc[0]);
                    atomicAdd(&cs[mbase + 2 * u + 1], (float)pc[1]);
                }
            }
        }

        // ---- odd step: consume vb2, prefetch va (kc+2)
        half8 e1 = ebuf[(kc + 1) & 7];
        if (kc + 9 < 16)
            ebuf[(kc + 1) & 7] = *(const half8*)&Arow[(kc + 9) * 32 + quad * 8];
        if (kc + 2 < 16) {
            #pragma unroll
            for (int dt = 0; dt < 4; ++dt)
                va[dt] = *(const half8*)&Vb[(size_t)(dt * 16) * 1024 + (kc + 2) * 32];
        }

        #pragma unroll
        for (int dt = 0; dt < 4; ++dt)
            acc[dt] = __builtin_amdgcn_mfma_f32_16x16x32_f16(e1, vb2[dt], acc[dt], 0, 0, 0);

        {
            half8 a2;
            #pragma unroll
            for (int j = 0; j < 8; ++j) a2[j] = (_Float16)((float)e1[j] * inv);
            const int mbase = mh * 512 + (kc + 1) * 32 + quad * 8;
            #pragma unroll
            for (int u = 0; u < 4; ++u) {
                half2v p2 = { a2[2 * u], a2[2 * u + 1] };
                int bits = *(int*)&p2;
                #pragma unroll
                for (int o = 1; o < 16; o <<= 1) {
                    int ob = __shfl_xor(bits, o);
                    half2v po = *(half2v*)&ob;
                    half2v pc = *(half2v*)&bits;
                    pc[0] = pc[0] + po[0]; pc[1] = pc[1] + po[1];
                    bits = *(int*)&pc;
                }
                if (col == 0) {
                    half2v pc = *(half2v*)&bits;
                    atomicAdd(&cs[mbase + 2 * u],     (float)pc[0]);
                    atomicAdd(&cs[mbase + 2 * u + 1], (float)pc[1]);
                }
            }
        }
    }

    if (mh == 1) {
        #pragma unroll
        for (int dt = 0; dt < 4; ++dt)
            *(floatx4*)&comb[lg][lane][dt * 4] = acc[dt];
    }
    __syncthreads();   // covers comb writes AND all cs atomics
    if (mh == 0) {
        #pragma unroll
        for (int dt = 0; dt < 4; ++dt)
            acc[dt] += *(floatx4*)&comb[lg][lane][dt * 4];
        #pragma unroll
        for (int r = 0; r < 4; ++r) {
            const int l = l0 + quad * 4 + r;
            const float ivr = inv_s[lg * 16 + quad * 4 + r];
            float* orow = out + (size_t)(b * 1024 + l) * 512 + h * 64;
            #pragma unroll
            for (int dt = 0; dt < 4; ++dt)
                orow[dt * 16 + col] = acc[dt][r] * ivr;
        }
    }
    atomicAdd(&wacc[b * 1024 + t],       cs[t]);
    atomicAdd(&wacc[b * 1024 + t + 512], cs[t + 512]);
}

// ---------- w finalize: w = softmax_m( (wacc/8)/len ), invalid -> 0
__global__ __launch_bounds__(256) void w_final(
    const float* __restrict__ wacc, const float* __restrict__ doc,
    float* __restrict__ wout)
{
    const int b = blockIdx.x;
    const int t = threadIdx.x;
    __shared__ float red[4];

    const float ds = doc[b];
    const int len = (int)ds;

    float v[4];
    float mx = -INFINITY;
    #pragma unroll
    for (int i = 0; i < 4; ++i) {
        const int m = t + 256 * i;
        const float raw = wacc[b * L_ + m];
        v[i] = (m < len) ? (raw * 0.125f) / ds : -INFINITY;
        mx = fmaxf(mx, v[i]);
    }
    #pragma unroll
    for (int off = 1; off < 64; off <<= 1) mx = fmaxf(mx, __shfl_xor(mx, off));
    if ((t & 63) == 0) red[t >> 6] = mx;
    __syncthreads();
    mx = fmaxf(fmaxf(red[0], red[1]), fmaxf(red[2], red[3]));

    float e[4];
    float sm = 0.f;
    #pragma unroll
    for (int i = 0; i < 4; ++i) {
        e[i] = (v[i] != -INFINITY) ? __expf(v[i] - mx) : 0.f;
        sm += e[i];
    }
    #pragma unroll
    for (int off = 1; off < 64; off <<= 1) sm += __shfl_xor(sm, off);
    __syncthreads();
    if ((t & 63) == 0) red[t >> 6] = sm;
    __syncthreads();
    sm = red[0] + red[1] + red[2] + red[3];
    const float inv = (sm > 0.f) ? 1.0f / sm : 0.f;

    #pragma unroll
    for (int i = 0; i < 4; ++i)
        wout[b * L_ + t + 256 * i] = e[i] * inv;
}

extern "C" void kernel_launch(void* const* d_in, const int* in_sizes, int n_in,
                              void* d_out, int out_size, void* d_ws, size_t ws_size,
                              hipStream_t stream)
{
    const float* K     = (const float*)d_in[0];
    const float* Q     = (const float*)d_in[1];
    const float* V     = (const float*)d_in[2];
    const float* doc   = (const float*)d_in[3];
    const float* gamma = (const float*)d_in[4];
    const float* beta  = (const float*)d_in[5];

    float* out  = (float*)d_out;
    float* wout = out + (size_t)4 * L_ * D_;

    _Float16* S    = (_Float16*)d_ws;               // 64 MB (e-values, flat)
    _Float16* K16  = S + (size_t)33554432;          // +4 MB
    _Float16* Q16  = K16 + 2097152;                 // +4 MB
    _Float16* Vt   = Q16 + 2097152;                 // +4 MB
    float*    spart = (float*)(Vt + 2097152);       // 2 MB (32768 x 16)
    float*    wacc  = spart + 524288 + 32768;       // 16 KB

    hipMemsetAsync(wacc, 0, 4096 * sizeof(float), stream);
    prep   <<<dim3(2560), dim3(256), 0, stream>>>(K, Q, V, K16, Q16, Vt);
    qk_ln  <<<dim3(1024), dim3(256), 0, stream>>>(K16, Q16, gamma, beta, doc, S, spart);
    pv     <<<dim3(512),  dim3(512), 0, stream>>>(S, Vt, spart, doc, out, wacc);
    w_final<<<dim3(4),    dim3(256), 0, stream>>>(wacc, doc, wout);
}